// Round 1
// baseline (17576.836 us; speedup 1.0000x reference)
//
#include <hip/hip_runtime.h>
#include <math.h>

namespace {
constexpr int kV = 12001;
constexpr int kE = 300;
constexpr int kR = 1024;
constexpr int kH = 512;
constexpr int kF = 2048;
constexpr int kB = 64;
constexpr int kT = 20;
constexpr int kL = 196;
}

// C[m,n] = beta*C[m,n] + sum_k A[row(m),k]*W[n,k] + bias[n]
// A: (rows x lda) row-major, W: (N x ldw) row-major. row(m) = ridx ? ridx[m*ridx_stride] : m
template<int BM, int BN, int BK, int TM, int TN>
__global__ __launch_bounds__((BM/TM)*(BN/TN))
void gemm_nt_kernel(const float* __restrict__ A, int lda,
                    const float* __restrict__ W, int ldw,
                    const float* __restrict__ bias,
                    float* __restrict__ C, int ldc,
                    int M, int N, int K,
                    const int* __restrict__ ridx, int ridx_stride,
                    int beta)
{
    constexpr int NT = (BM/TM)*(BN/TN);
    __shared__ float sA[BK][BM+4];
    __shared__ float sW[BK][BN+4];
    const int tid = threadIdx.x;
    const int m0 = blockIdx.y * BM;
    const int n0 = blockIdx.x * BN;
    const int tn = tid % (BN/TN);
    const int tm = tid / (BN/TN);
    float acc[TM][TN] = {};

    for (int k0 = 0; k0 < K; k0 += BK) {
        #pragma unroll
        for (int i = tid; i < BM*BK; i += NT) {
            const int r  = i / BK;
            const int kk = i % BK;
            const int m  = m0 + r;
            const int k  = k0 + kk;
            float v = 0.f;
            if (m < M && k < K) {
                const int arow = ridx ? ridx[(size_t)m * ridx_stride] : m;
                v = A[(size_t)arow * lda + k];
            }
            sA[kk][r] = v;
        }
        #pragma unroll
        for (int i = tid; i < BN*BK; i += NT) {
            const int r  = i / BK;
            const int kk = i % BK;
            const int n  = n0 + r;
            const int k  = k0 + kk;
            float v = 0.f;
            if (n < N && k < K) v = W[(size_t)n * ldw + k];
            sW[kk][r] = v;
        }
        __syncthreads();
        #pragma unroll
        for (int kk = 0; kk < BK; ++kk) {
            float av[TM], bv[TN];
            #pragma unroll
            for (int i = 0; i < TM; ++i) av[i] = sA[kk][tm*TM + i];
            #pragma unroll
            for (int j = 0; j < TN; ++j) bv[j] = sW[kk][tn*TN + j];
            #pragma unroll
            for (int i = 0; i < TM; ++i)
                #pragma unroll
                for (int j = 0; j < TN; ++j)
                    acc[i][j] += av[i] * bv[j];
        }
        __syncthreads();
    }

    #pragma unroll
    for (int i = 0; i < TM; ++i) {
        const int m = m0 + tm*TM + i;
        if (m >= M) continue;
        #pragma unroll
        for (int j = 0; j < TN; ++j) {
            const int n = n0 + tn*TN + j;
            if (n >= N) continue;
            float v = acc[i][j];
            if (bias) v += bias[n];
            float* p = C + (size_t)m * ldc + n;
            if (beta) v += *p;
            *p = v;
        }
    }
}

// e[b,l] = sum_h tanh(p_att[b,l,h] + att_h[b,h]) * alpha_w[h] + alpha_b
__global__ __launch_bounds__(256)
void att_e_kernel(const float* __restrict__ p_att,
                  const float* __restrict__ att_h,
                  const float* __restrict__ alpha_w,
                  const float* __restrict__ alpha_b,
                  float* __restrict__ e)
{
    const int wave = threadIdx.x >> 6;
    const int lane = threadIdx.x & 63;
    const int row  = blockIdx.x * 4 + wave;
    if (row >= kB * kL) return;
    const int b = row / kL;
    const float* pr = p_att + (size_t)row * kH;
    const float* ah = att_h + (size_t)b * kH;
    float acc = 0.f;
    #pragma unroll
    for (int h = lane; h < kH; h += 64)
        acc += tanhf(pr[h] + ah[h]) * alpha_w[h];
    #pragma unroll
    for (int off = 32; off > 0; off >>= 1)
        acc += __shfl_down(acc, off);
    if (lane == 0) e[row] = acc + alpha_b[0];
}

// per-block: (fchunk, b). softmax over L (redundant per fchunk) + att_res[b,f] = sum_l w[l]*att_feats[b,l,f]
__global__ __launch_bounds__(256)
void att_softmax_res_kernel(const float* __restrict__ e,
                            const float* __restrict__ att_feats,
                            float* __restrict__ att_res)
{
    __shared__ float wsm[kL];
    __shared__ float red[256];
    const int b   = blockIdx.y;
    const int tid = threadIdx.x;

    float v = (tid < kL) ? e[b * kL + tid] : -1e30f;
    red[tid] = v; __syncthreads();
    for (int s = 128; s > 0; s >>= 1) {
        if (tid < s) red[tid] = fmaxf(red[tid], red[tid + s]);
        __syncthreads();
    }
    const float mx = red[0];
    __syncthreads();
    float ex = (tid < kL) ? expf(v - mx) : 0.f;
    red[tid] = ex; __syncthreads();
    for (int s = 128; s > 0; s >>= 1) {
        if (tid < s) red[tid] += red[tid + s];
        __syncthreads();
    }
    const float sum = red[0];
    if (tid < kL) wsm[tid] = ex / sum;
    __syncthreads();

    const int f = blockIdx.x * 256 + tid;
    const float* af = att_feats + (size_t)b * kL * kF + f;
    float acc = 0.f;
    #pragma unroll 4
    for (int l = 0; l < kL; ++l)
        acc += wsm[l] * af[(size_t)l * kF];
    att_res[(size_t)b * kF + f] = acc;
}

// gates + state update. sums: [B,5R]; cols [3R,5R) already hold itr after a2c accum.
__global__ __launch_bounds__(256)
void lstm_gates_kernel(const float* __restrict__ sums,
                       float* __restrict__ h, float* __restrict__ c)
{
    const int idx = blockIdx.x * 256 + threadIdx.x;
    if (idx >= kB * kR) return;
    const int b = idx / kR;
    const int r = idx % kR;
    const float* s = sums + (size_t)b * 5 * kR;
    const float ing = 1.f / (1.f + expf(-s[r]));
    const float fg  = 1.f / (1.f + expf(-s[kR + r]));
    const float og  = 1.f / (1.f + expf(-s[2*kR + r]));
    const float g   = fmaxf(s[3*kR + r], s[4*kR + r]);
    const float nc  = fg * c[idx] + ing * g;
    const float nh  = og * tanhf(nc);
    c[idx] = nc;
    h[idx] = nh;
}

// in-place log_softmax over V for row b at out + b*ldc
__global__ __launch_bounds__(256)
void log_softmax_kernel(float* __restrict__ out, int ldc)
{
    __shared__ float red[256];
    const int b = blockIdx.x;
    const int tid = threadIdx.x;
    float* row = out + (size_t)b * ldc;

    float mx = -1e30f;
    for (int v = tid; v < kV; v += 256) mx = fmaxf(mx, row[v]);
    red[tid] = mx; __syncthreads();
    for (int s = 128; s > 0; s >>= 1) {
        if (tid < s) red[tid] = fmaxf(red[tid], red[tid + s]);
        __syncthreads();
    }
    mx = red[0];
    __syncthreads();

    float sum = 0.f;
    for (int v = tid; v < kV; v += 256) sum += expf(row[v] - mx);
    red[tid] = sum; __syncthreads();
    for (int s = 128; s > 0; s >>= 1) {
        if (tid < s) red[tid] += red[tid + s];
        __syncthreads();
    }
    const float ls = mx + logf(red[0]);

    for (int v = tid; v < kV; v += 256) row[v] = row[v] - ls;
}

extern "C" void kernel_launch(void* const* d_in, const int* in_sizes, int n_in,
                              void* d_out, int out_size, void* d_ws, size_t ws_size,
                              hipStream_t stream)
{
    const int*   seq       = (const int*)  d_in[0];
    const float* att_feats = (const float*)d_in[1];
    const float* embed_w   = (const float*)d_in[2];
    const float* ctx2att_w = (const float*)d_in[3];
    const float* ctx2att_b = (const float*)d_in[4];
    const float* h2att_w   = (const float*)d_in[5];
    const float* h2att_b   = (const float*)d_in[6];
    const float* alpha_w   = (const float*)d_in[7];
    const float* alpha_b   = (const float*)d_in[8];
    const float* i2h_w     = (const float*)d_in[9];
    const float* i2h_b     = (const float*)d_in[10];
    const float* h2h_w     = (const float*)d_in[11];
    const float* h2h_b     = (const float*)d_in[12];
    const float* a2c_w     = (const float*)d_in[13];
    const float* a2c_b     = (const float*)d_in[14];
    const float* logit_w   = (const float*)d_in[15];
    const float* logit_b   = (const float*)d_in[16];
    float* out = (float*)d_out;

    float* ws      = (float*)d_ws;
    float* p_att   = ws;                               // kB*kL*kH
    float* att_h   = p_att   + (size_t)kB*kL*kH;       // kB*kH
    float* e_buf   = att_h   + (size_t)kB*kH;          // kB*kL
    float* att_res = e_buf   + (size_t)kB*kL;          // kB*kF
    float* sums    = att_res + (size_t)kB*kF;          // kB*5*kR
    float* hbuf    = sums    + (size_t)kB*5*kR;        // kB*kR
    float* cbuf    = hbuf    + (size_t)kB*kR;          // kB*kR

    hipMemsetAsync(hbuf, 0, (size_t)kB*kR*sizeof(float), stream);
    hipMemsetAsync(cbuf, 0, (size_t)kB*kR*sizeof(float), stream);

    // p_att = att_feats @ ctx2att_w.T + ctx2att_b   (12544 x 512, K=2048)
    gemm_nt_kernel<64,64,32,4,4><<<dim3(kH/64, (kB*kL)/64), 256, 0, stream>>>(
        att_feats, kF, ctx2att_w, kF, ctx2att_b, p_att, kH,
        kB*kL, kH, kF, nullptr, 0, 0);

    for (int t = 0; t < kT; ++t) {
        // att_h = h @ h2att_w.T + h2att_b          (64 x 512, K=1024)
        gemm_nt_kernel<64,32,32,2,4><<<dim3(kH/32, 1), 256, 0, stream>>>(
            hbuf, kR, h2att_w, kR, h2att_b, att_h, kH,
            kB, kH, kR, nullptr, 0, 0);

        att_e_kernel<<<dim3((kB*kL)/4), 256, 0, stream>>>(
            p_att, att_h, alpha_w, alpha_b, e_buf);

        att_softmax_res_kernel<<<dim3(kF/256, kB), 256, 0, stream>>>(
            e_buf, att_feats, att_res);

        // sums = xt @ i2h_w.T + i2h_b              (64 x 5120, K=300, gathered rows)
        gemm_nt_kernel<64,32,32,2,4><<<dim3(5*kR/32, 1), 256, 0, stream>>>(
            embed_w, kE, i2h_w, kE, i2h_b, sums, 5*kR,
            kB, 5*kR, kE, seq + t, kT, 0);

        // sums += h @ h2h_w.T + h2h_b              (64 x 5120, K=1024)
        gemm_nt_kernel<64,32,32,2,4><<<dim3(5*kR/32, 1), 256, 0, stream>>>(
            hbuf, kR, h2h_w, kR, h2h_b, sums, 5*kR,
            kB, 5*kR, kR, nullptr, 0, 1);

        // sums[:,3R:] += att_res @ a2c_w.T + a2c_b (64 x 2048, K=2048)
        gemm_nt_kernel<64,32,32,2,4><<<dim3(2*kR/32, 1), 256, 0, stream>>>(
            att_res, kF, a2c_w, kF, a2c_b, sums + 3*kR, 5*kR,
            kB, 2*kR, kF, nullptr, 0, 1);

        lstm_gates_kernel<<<dim3(kB*kR/256), 256, 0, stream>>>(sums, hbuf, cbuf);

        // logits = nh @ logit_w.T + logit_b -> out[:, t, :]   (64 x 12001, K=1024)
        gemm_nt_kernel<64,32,32,2,4><<<dim3((kV+31)/32, 1), 256, 0, stream>>>(
            hbuf, kR, logit_w, kR, logit_b, out + (size_t)t*kV, kT*kV,
            kB, kV, kR, nullptr, 0, 0);

        log_softmax_kernel<<<dim3(kB), 256, 0, stream>>>(out + (size_t)t*kV, kT*kV);
    }
}

// Round 2
// 10612.493 us; speedup vs baseline: 1.6562x; 1.6562x over previous
//
#include <hip/hip_runtime.h>
#include <math.h>

namespace {
constexpr int kV = 12001;
constexpr int kE = 300;
constexpr int kR = 1024;
constexpr int kH = 512;
constexpr int kF = 2048;
constexpr int kB = 64;
constexpr int kT = 20;
constexpr int kL = 196;
}

// ---------------------------------------------------------------------------
// Big GEMM: C[m,n] = sum_k A[row(m),k]*W[n,k] + bias[n]
// BM=BN=128, BK=16, 8x8 per thread (chunked 4+4 mapping), 256 threads.
// ---------------------------------------------------------------------------
__global__ __launch_bounds__(256)
void gemm_big(const float* __restrict__ A, int lda,
              const float* __restrict__ W, int ldw,
              const float* __restrict__ bias,
              float* __restrict__ C, int ldc,
              int M, int N, int K,
              const int* __restrict__ ridx)
{
    constexpr int BM = 128, BN = 128, BK = 16;
    __shared__ float sA[BK][BM + 1];
    __shared__ float sW[BK][BN + 1];
    const int tid = threadIdx.x;
    const int m0 = blockIdx.y * BM;
    const int n0 = blockIdx.x * BN;
    const int tn = tid & 15;
    const int tm = tid >> 4;
    float acc[8][8] = {};

    for (int k0 = 0; k0 < K; k0 += BK) {
        #pragma unroll
        for (int i = tid; i < BM * 4; i += 256) {
            const int kk = (i & 3) * 4;
            const int r  = i >> 2;
            const int m  = m0 + r;
            const int k  = k0 + kk;
            float4 v = make_float4(0.f, 0.f, 0.f, 0.f);
            if (m < M && k < K) {
                const int arow = ridx ? ridx[m] : m;
                const float* p = A + (size_t)arow * lda + k;
                if (k + 4 <= K) v = *(const float4*)p;
                else { v.x = p[0]; if (k+1 < K) v.y = p[1]; if (k+2 < K) v.z = p[2]; }
            }
            sA[kk][r] = v.x; sA[kk+1][r] = v.y; sA[kk+2][r] = v.z; sA[kk+3][r] = v.w;
        }
        #pragma unroll
        for (int i = tid; i < BN * 4; i += 256) {
            const int kk = (i & 3) * 4;
            const int r  = i >> 2;
            const int n  = n0 + r;
            const int k  = k0 + kk;
            float4 v = make_float4(0.f, 0.f, 0.f, 0.f);
            if (n < N && k < K) {
                const float* p = W + (size_t)n * ldw + k;
                if (k + 4 <= K) v = *(const float4*)p;
                else { v.x = p[0]; if (k+1 < K) v.y = p[1]; if (k+2 < K) v.z = p[2]; }
            }
            sW[kk][r] = v.x; sW[kk+1][r] = v.y; sW[kk+2][r] = v.z; sW[kk+3][r] = v.w;
        }
        __syncthreads();
        #pragma unroll
        for (int kk = 0; kk < BK; ++kk) {
            float av[8], bv[8];
            #pragma unroll
            for (int c = 0; c < 2; ++c)
                #pragma unroll
                for (int i = 0; i < 4; ++i) {
                    av[c*4 + i] = sA[kk][c*64 + tm*4 + i];
                    bv[c*4 + i] = sW[kk][c*64 + tn*4 + i];
                }
            #pragma unroll
            for (int i = 0; i < 8; ++i)
                #pragma unroll
                for (int j = 0; j < 8; ++j)
                    acc[i][j] += av[i] * bv[j];
        }
        __syncthreads();
    }

    #pragma unroll
    for (int i = 0; i < 8; ++i) {
        const int m = m0 + (i >> 2)*64 + tm*4 + (i & 3);
        if (m >= M) continue;
        float* crow = C + (size_t)m * ldc;
        #pragma unroll
        for (int j = 0; j < 8; ++j) {
            const int n = n0 + (j >> 2)*64 + tn*4 + (j & 3);
            if (n >= N) continue;
            crow[n] = acc[i][j] + (bias ? bias[n] : 0.f);
        }
    }
}

// ---------------------------------------------------------------------------
// Small-M GEMM: BM=64, BN=32, BK=32, 4x4 per thread, 128 threads.
// C[m,n] = beta*C[m,n] + sum_k A[m,k]*W[n,k] + bias[n] + add[m*ldadd+n]
// ---------------------------------------------------------------------------
__global__ __launch_bounds__(128)
void gemm_small(const float* __restrict__ A, int lda,
                const float* __restrict__ W, int ldw,
                const float* __restrict__ bias,
                const float* __restrict__ add, int ldadd,
                float* __restrict__ C, int ldc,
                int M, int N, int K, int beta)
{
    constexpr int BM = 64, BN = 32, BK = 32;
    __shared__ float sA[BK][BM + 1];
    __shared__ float sW[BK][BN + 1];
    const int tid = threadIdx.x;
    const int m0 = blockIdx.y * BM;
    const int n0 = blockIdx.x * BN;
    const int tn = tid & 7;
    const int tm = tid >> 3;
    float acc[4][4] = {};

    for (int k0 = 0; k0 < K; k0 += BK) {
        #pragma unroll
        for (int i = tid; i < BM * 8; i += 128) {
            const int kk = (i & 7) * 4;
            const int r  = i >> 3;
            const int m  = m0 + r;
            const int k  = k0 + kk;
            float4 v = make_float4(0.f, 0.f, 0.f, 0.f);
            if (m < M && k < K) {
                const float* p = A + (size_t)m * lda + k;
                if (k + 4 <= K) v = *(const float4*)p;
                else { v.x = p[0]; if (k+1 < K) v.y = p[1]; if (k+2 < K) v.z = p[2]; }
            }
            sA[kk][r] = v.x; sA[kk+1][r] = v.y; sA[kk+2][r] = v.z; sA[kk+3][r] = v.w;
        }
        #pragma unroll
        for (int i = tid; i < BN * 8; i += 128) {
            const int kk = (i & 7) * 4;
            const int r  = i >> 3;
            const int n  = n0 + r;
            const int k  = k0 + kk;
            float4 v = make_float4(0.f, 0.f, 0.f, 0.f);
            if (n < N && k < K) {
                const float* p = W + (size_t)n * ldw + k;
                if (k + 4 <= K) v = *(const float4*)p;
                else { v.x = p[0]; if (k+1 < K) v.y = p[1]; if (k+2 < K) v.z = p[2]; }
            }
            sW[kk][r] = v.x; sW[kk+1][r] = v.y; sW[kk+2][r] = v.z; sW[kk+3][r] = v.w;
        }
        __syncthreads();
        #pragma unroll
        for (int kk = 0; kk < BK; ++kk) {
            float av[4], bv[4];
            #pragma unroll
            for (int i = 0; i < 4; ++i) av[i] = sA[kk][tm*4 + i];
            #pragma unroll
            for (int j = 0; j < 4; ++j) bv[j] = sW[kk][tn*4 + j];
            #pragma unroll
            for (int i = 0; i < 4; ++i)
                #pragma unroll
                for (int j = 0; j < 4; ++j)
                    acc[i][j] += av[i] * bv[j];
        }
        __syncthreads();
    }

    #pragma unroll
    for (int i = 0; i < 4; ++i) {
        const int m = m0 + tm*4 + i;
        if (m >= M) continue;
        float* crow = C + (size_t)m * ldc;
        const float* arow = add ? add + (size_t)m * ldadd : nullptr;
        #pragma unroll
        for (int j = 0; j < 4; ++j) {
            const int n = n0 + tn*4 + j;
            if (n >= N) continue;
            float v = acc[i][j];
            if (bias) v += bias[n];
            if (arow) v += arow[n];
            if (beta) v += crow[n];
            crow[n] = v;
        }
    }
}

// e[b,l] = sum_h tanh(p_att[b,l,h] + att_h[b,h]) * alpha_w[h] + alpha_b
__global__ __launch_bounds__(256)
void att_e_kernel(const float* __restrict__ p_att,
                  const float* __restrict__ att_h,
                  const float* __restrict__ alpha_w,
                  const float* __restrict__ alpha_b,
                  float* __restrict__ e)
{
    const int wave = threadIdx.x >> 6;
    const int lane = threadIdx.x & 63;
    const int row  = blockIdx.x * 4 + wave;
    if (row >= kB * kL) return;
    const int b = row / kL;
    const float4* pr = (const float4*)(p_att + (size_t)row * kH);
    const float4* ah = (const float4*)(att_h + (size_t)b * kH);
    const float4* aw = (const float4*)alpha_w;
    float acc = 0.f;
    #pragma unroll
    for (int h4 = lane; h4 < kH/4; h4 += 64) {
        float4 p = pr[h4], a = ah[h4], w = aw[h4];
        acc += tanhf(p.x + a.x) * w.x + tanhf(p.y + a.y) * w.y
             + tanhf(p.z + a.z) * w.z + tanhf(p.w + a.w) * w.w;
    }
    #pragma unroll
    for (int off = 32; off > 0; off >>= 1)
        acc += __shfl_down(acc, off);
    if (lane == 0) e[row] = acc + alpha_b[0];
}

// per-block (fchunk,b): softmax over L + att_res[b,f] = sum_l w[l]*att_feats[b,l,f]
__global__ __launch_bounds__(256)
void att_softmax_res_kernel(const float* __restrict__ e,
                            const float* __restrict__ att_feats,
                            float* __restrict__ att_res)
{
    __shared__ float wsm[kL];
    __shared__ float red[256];
    const int b   = blockIdx.y;
    const int tid = threadIdx.x;

    float v = (tid < kL) ? e[b * kL + tid] : -1e30f;
    red[tid] = v; __syncthreads();
    for (int s = 128; s > 0; s >>= 1) {
        if (tid < s) red[tid] = fmaxf(red[tid], red[tid + s]);
        __syncthreads();
    }
    const float mx = red[0];
    __syncthreads();
    float ex = (tid < kL) ? expf(v - mx) : 0.f;
    red[tid] = ex; __syncthreads();
    for (int s = 128; s > 0; s >>= 1) {
        if (tid < s) red[tid] += red[tid + s];
        __syncthreads();
    }
    const float sum = red[0];
    if (tid < kL) wsm[tid] = ex / sum;
    __syncthreads();

    const int f = blockIdx.x * 256 + tid;
    const float* af = att_feats + (size_t)b * kL * kF + f;
    float acc = 0.f;
    #pragma unroll 4
    for (int l = 0; l < kL; ++l)
        acc += wsm[l] * af[(size_t)l * kF];
    att_res[(size_t)b * kF + f] = acc;
}

// gates + state update; also records h into h_all[b*kT + t]
__global__ __launch_bounds__(256)
void lstm_gates_kernel(const float* __restrict__ sums,
                       float* __restrict__ h, float* __restrict__ c,
                       float* __restrict__ h_all, int t)
{
    const int idx = blockIdx.x * 256 + threadIdx.x;
    if (idx >= kB * kR) return;
    const int b = idx / kR;
    const int r = idx % kR;
    const float* s = sums + (size_t)b * 5 * kR;
    const float ing = 1.f / (1.f + expf(-s[r]));
    const float fg  = 1.f / (1.f + expf(-s[kR + r]));
    const float og  = 1.f / (1.f + expf(-s[2*kR + r]));
    const float g   = fmaxf(s[3*kR + r], s[4*kR + r]);
    const float nc  = fg * c[idx] + ing * g;
    const float nh  = og * tanhf(nc);
    c[idx] = nc;
    h[idx] = nh;
    h_all[(size_t)(b * kT + t) * kR + r] = nh;
}

// in-place log_softmax over V; one block per row (grid = kB*kT)
__global__ __launch_bounds__(256)
void log_softmax_kernel(float* __restrict__ out)
{
    __shared__ float red[256];
    const int tid = threadIdx.x;
    float* row = out + (size_t)blockIdx.x * kV;

    float mx = -1e30f;
    for (int v = tid; v < kV; v += 256) mx = fmaxf(mx, row[v]);
    red[tid] = mx; __syncthreads();
    for (int s = 128; s > 0; s >>= 1) {
        if (tid < s) red[tid] = fmaxf(red[tid], red[tid + s]);
        __syncthreads();
    }
    mx = red[0];
    __syncthreads();

    float sum = 0.f;
    for (int v = tid; v < kV; v += 256) sum += expf(row[v] - mx);
    red[tid] = sum; __syncthreads();
    for (int s = 128; s > 0; s >>= 1) {
        if (tid < s) red[tid] += red[tid + s];
        __syncthreads();
    }
    const float ls = mx + logf(red[0]);

    for (int v = tid; v < kV; v += 256) row[v] -= ls;
}

extern "C" void kernel_launch(void* const* d_in, const int* in_sizes, int n_in,
                              void* d_out, int out_size, void* d_ws, size_t ws_size,
                              hipStream_t stream)
{
    const int*   seq       = (const int*)  d_in[0];
    const float* att_feats = (const float*)d_in[1];
    const float* embed_w   = (const float*)d_in[2];
    const float* ctx2att_w = (const float*)d_in[3];
    const float* ctx2att_b = (const float*)d_in[4];
    const float* h2att_w   = (const float*)d_in[5];
    const float* h2att_b   = (const float*)d_in[6];
    const float* alpha_w   = (const float*)d_in[7];
    const float* alpha_b   = (const float*)d_in[8];
    const float* i2h_w     = (const float*)d_in[9];
    const float* i2h_b     = (const float*)d_in[10];
    const float* h2h_w     = (const float*)d_in[11];
    const float* h2h_b     = (const float*)d_in[12];
    const float* a2c_w     = (const float*)d_in[13];
    const float* a2c_b     = (const float*)d_in[14];
    const float* logit_w   = (const float*)d_in[15];
    const float* logit_b   = (const float*)d_in[16];
    float* out = (float*)d_out;

    float* ws      = (float*)d_ws;
    float* p_att   = ws;                                   // kB*kL*kH
    float* att_h   = p_att   + (size_t)kB*kL*kH;           // kB*kH
    float* e_buf   = att_h   + (size_t)kB*kH;              // kB*kL
    float* att_res = e_buf   + (size_t)kB*kL;              // kB*kF
    float* sums    = att_res + (size_t)kB*kF;              // kB*5*kR
    float* hcur    = sums    + (size_t)kB*5*kR;            // kB*kR
    float* cbuf    = hcur    + (size_t)kB*kR;              // kB*kR
    float* h_all   = cbuf    + (size_t)kB*kR;              // kB*kT*kR
    float* i2h_pre = h_all   + (size_t)kB*kT*kR;           // kB*kT*5*kR

    hipMemsetAsync(hcur, 0, (size_t)kB*kR*sizeof(float), stream);
    hipMemsetAsync(cbuf, 0, (size_t)kB*kR*sizeof(float), stream);

    // p_att = att_feats @ ctx2att_w.T + b     (12544 x 512, K=2048)
    gemm_big<<<dim3(kH/128, kB*kL/128), 256, 0, stream>>>(
        att_feats, kF, ctx2att_w, kF, ctx2att_b, p_att, kH,
        kB*kL, kH, kF, nullptr);

    // i2h_pre[b*T+t] = embed_w[seq[b,t]] @ i2h_w.T + i2h_b   (1280 x 5120, K=300)
    gemm_big<<<dim3(5*kR/128, kB*kT/128), 256, 0, stream>>>(
        embed_w, kE, i2h_w, kE, i2h_b, i2h_pre, 5*kR,
        kB*kT, 5*kR, kE, seq);

    for (int t = 0; t < kT; ++t) {
        // att_h = h @ h2att_w.T + b           (64 x 512, K=1024)
        gemm_small<<<dim3(kH/32, 1), 128, 0, stream>>>(
            hcur, kR, h2att_w, kR, h2att_b, nullptr, 0, att_h, kH,
            kB, kH, kR, 0);

        att_e_kernel<<<dim3(kB*kL/4), 256, 0, stream>>>(
            p_att, att_h, alpha_w, alpha_b, e_buf);

        att_softmax_res_kernel<<<dim3(kF/256, kB), 256, 0, stream>>>(
            e_buf, att_feats, att_res);

        // sums = h @ h2h_w.T + h2h_b + i2h_pre[:,t,:]   (64 x 5120, K=1024)
        gemm_small<<<dim3(5*kR/32, 1), 128, 0, stream>>>(
            hcur, kR, h2h_w, kR, h2h_b,
            i2h_pre + (size_t)t*5*kR, kT*5*kR, sums, 5*kR,
            kB, 5*kR, kR, 0);

        // sums[:,3R:] += att_res @ a2c_w.T + a2c_b      (64 x 2048, K=2048)
        gemm_small<<<dim3(2*kR/32, 1), 128, 0, stream>>>(
            att_res, kF, a2c_w, kF, a2c_b, nullptr, 0, sums + 3*kR, 5*kR,
            kB, 2*kR, kF, 1);

        lstm_gates_kernel<<<dim3(kB*kR/256), 256, 0, stream>>>(
            sums, hcur, cbuf, h_all, t);
    }

    // logits = h_all @ logit_w.T + logit_b  ->  out rows (b*T+t)   (1280 x 12001, K=1024)
    gemm_big<<<dim3((kV + 127)/128, kB*kT/128), 256, 0, stream>>>(
        h_all, kR, logit_w, kR, logit_b, out, kV,
        kB*kT, kV, kR, nullptr);

    log_softmax_kernel<<<dim3(kB*kT), 256, 0, stream>>>(out);
}

// Round 6
// 3948.448 us; speedup vs baseline: 4.4516x; 2.6878x over previous
//
#include <hip/hip_runtime.h>
#include <math.h>

namespace {
constexpr int kV = 12001;
constexpr int kE = 300;
constexpr int kR = 1024;
constexpr int kH = 512;
constexpr int kF = 2048;
constexpr int kB = 64;
constexpr int kT = 20;
constexpr int kL = 196;
}

typedef __attribute__((ext_vector_type(8))) short short8;
typedef __attribute__((ext_vector_type(4))) float f32x4;

__device__ __forceinline__ unsigned short f2bf(float f) {
    unsigned u = __builtin_bit_cast(unsigned, f);
    u = (u + 0x7fffu + ((u >> 16) & 1u)) >> 16;
    return (unsigned short)u;
}
__device__ __forceinline__ float bf2f(unsigned short h) {
    unsigned u = ((unsigned)h) << 16;
    return __builtin_bit_cast(float, u);
}

// ---------------------------------------------------------------------------
// Split-bf16 MFMA GEMM (fp32 in, fp32 out, ~fp32 accuracy):
// C[m,n] = sum_k A[row(m),k]*W[n,k] + bias[n]
// A = Ah + Al (bf16 pair), W = Wh + Wl; A*W ~= Ah*Wh + Ah*Wl + Al*Wh.
// 128x128 tile, BK=32, 4 waves (2x2), each wave 64x64 via 4x4 mfma 16x16x32.
// ---------------------------------------------------------------------------
template<bool GATHER>
__global__ __launch_bounds__(256)
void gemm_split_kernel(const float* __restrict__ A, int lda,
                       const float* __restrict__ W, int ldw,
                       const float* __restrict__ bias,
                       float* __restrict__ C, int ldc,
                       int M, int N, int K,
                       const int* __restrict__ ridx)
{
    __shared__ unsigned short sAh[128][40];
    __shared__ unsigned short sAl[128][40];
    __shared__ unsigned short sWh[128][40];
    __shared__ unsigned short sWl[128][40];
    const int tid = threadIdx.x;
    const int m0 = blockIdx.y * 128;
    const int n0 = blockIdx.x * 128;
    const int wave = tid >> 6, lane = tid & 63;
    const int wm = wave >> 1, wn = wave & 1;
    const int lrow = lane & 15, lkg = lane >> 4;

    f32x4 acc[4][4];
    #pragma unroll
    for (int mi = 0; mi < 4; ++mi)
        #pragma unroll
        for (int ni = 0; ni < 4; ++ni)
            acc[mi][ni] = (f32x4){0.f, 0.f, 0.f, 0.f};

    for (int k0 = 0; k0 < K; k0 += 32) {
        for (int g = tid; g < 512; g += 256) {
            const int r = g >> 2, q = g & 3;
            const int k = k0 + q * 8;
            short8 vh = (short8){0,0,0,0,0,0,0,0};
            short8 vl = (short8){0,0,0,0,0,0,0,0};
            const int m = m0 + r;
            if (m < M && k < K) {
                const int row = GATHER ? ridx[m] : m;
                const float* src = A + (size_t)row * lda + k;
                float va[8];
                if (k + 8 <= K) {
                    float4 f0 = *(const float4*)src;
                    float4 f1 = *(const float4*)(src + 4);
                    va[0]=f0.x; va[1]=f0.y; va[2]=f0.z; va[3]=f0.w;
                    va[4]=f1.x; va[5]=f1.y; va[6]=f1.z; va[7]=f1.w;
                } else {
                    #pragma unroll
                    for (int j = 0; j < 8; ++j) va[j] = (k + j < K) ? src[j] : 0.f;
                }
                #pragma unroll
                for (int j = 0; j < 8; ++j) {
                    const unsigned short hi = f2bf(va[j]);
                    ((short*)&vh)[j] = (short)hi;
                    ((short*)&vl)[j] = (short)f2bf(va[j] - bf2f(hi));
                }
            }
            *(short8*)&sAh[r][q * 8] = vh;
            *(short8*)&sAl[r][q * 8] = vl;
        }
        for (int g = tid; g < 512; g += 256) {
            const int r = g >> 2, q = g & 3;
            const int k = k0 + q * 8;
            short8 vh = (short8){0,0,0,0,0,0,0,0};
            short8 vl = (short8){0,0,0,0,0,0,0,0};
            const int n = n0 + r;
            if (n < N && k < K) {
                const float* src = W + (size_t)n * ldw + k;
                float va[8];
                if (k + 8 <= K) {
                    float4 f0 = *(const float4*)src;
                    float4 f1 = *(const float4*)(src + 4);
                    va[0]=f0.x; va[1]=f0.y; va[2]=f0.z; va[3]=f0.w;
                    va[4]=f1.x; va[5]=f1.y; va[6]=f1.z; va[7]=f1.w;
                } else {
                    #pragma unroll
                    for (int j = 0; j < 8; ++j) va[j] = (k + j < K) ? src[j] : 0.f;
                }
                #pragma unroll
                for (int j = 0; j < 8; ++j) {
                    const unsigned short hi = f2bf(va[j]);
                    ((short*)&vh)[j] = (short)hi;
                    ((short*)&vl)[j] = (short)f2bf(va[j] - bf2f(hi));
                }
            }
            *(short8*)&sWh[r][q * 8] = vh;
            *(short8*)&sWl[r][q * 8] = vl;
        }
        __syncthreads();

        short8 ah[4], al[4], bh[4], bl[4];
        #pragma unroll
        for (int mi = 0; mi < 4; ++mi) {
            ah[mi] = *(const short8*)&sAh[wm * 64 + mi * 16 + lrow][lkg * 8];
            al[mi] = *(const short8*)&sAl[wm * 64 + mi * 16 + lrow][lkg * 8];
        }
        #pragma unroll
        for (int ni = 0; ni < 4; ++ni) {
            bh[ni] = *(const short8*)&sWh[wn * 64 + ni * 16 + lrow][lkg * 8];
            bl[ni] = *(const short8*)&sWl[wn * 64 + ni * 16 + lrow][lkg * 8];
        }
        #pragma unroll
        for (int mi = 0; mi < 4; ++mi)
            #pragma unroll
            for (int ni = 0; ni < 4; ++ni) {
                acc[mi][ni] = __builtin_amdgcn_mfma_f32_16x16x32_bf16(ah[mi], bh[ni], acc[mi][ni], 0, 0, 0);
                acc[mi][ni] = __builtin_amdgcn_mfma_f32_16x16x32_bf16(ah[mi], bl[ni], acc[mi][ni], 0, 0, 0);
                acc[mi][ni] = __builtin_amdgcn_mfma_f32_16x16x32_bf16(al[mi], bh[ni], acc[mi][ni], 0, 0, 0);
            }
        __syncthreads();
    }

    // epilogue: C row = (lane>>4)*4 + reg, col = lane&15 (m89-verified layout)
    #pragma unroll
    for (int mi = 0; mi < 4; ++mi) {
        const int mbase = m0 + wm * 64 + mi * 16 + lkg * 4;
        #pragma unroll
        for (int ni = 0; ni < 4; ++ni) {
            const int n = n0 + wn * 64 + ni * 16 + lrow;
            if (n >= N) continue;
            const float bb = bias ? bias[n] : 0.f;
            #pragma unroll
            for (int r = 0; r < 4; ++r) {
                const int m = mbase + r;
                if (m >= M) continue;
                C[(size_t)m * ldc + n] = acc[mi][ni][r] + bb;
            }
        }
    }
}

// ---------------------------------------------------------------------------
// att_h[b,j] = sum_k h_in[b,k]*h2att_w[j,k] + h2att_b[j]
// grid (4, 64) = (jchunk, b); 2 threads per j (512-long half-dots).
// ---------------------------------------------------------------------------
__global__ __launch_bounds__(256)
void att_h_kernel(const float* __restrict__ h_in,
                  const float* __restrict__ w,
                  const float* __restrict__ bias,
                  float* __restrict__ att_h)
{
    __shared__ float hs[kR];
    const int b = blockIdx.y, jc = blockIdx.x;
    const int tid = threadIdx.x;
    *(float4*)&hs[tid * 4] = *(const float4*)&h_in[b * kR + tid * 4];
    __syncthreads();
    const int j = jc * 128 + (tid >> 1);
    const int half = tid & 1;
    const float4* wr = (const float4*)(w + (size_t)j * kR + half * 512);
    const float4* hp = (const float4*)(hs + half * 512);
    float acc = 0.f;
    #pragma unroll 8
    for (int q = 0; q < 128; ++q) {
        const float4 wv = wr[q], hv = hp[q];
        acc += wv.x * hv.x + wv.y * hv.y + wv.z * hv.z + wv.w * hv.w;
    }
    acc += __shfl_xor(acc, 1, 64);
    if (!half) att_h[b * kH + j] = acc + bias[j];
}

// ---------------------------------------------------------------------------
// e[b,l] = sum_h tanh(p_att[b,l,h] + att_h[b,h]) * alpha_w[h] + alpha_b
// ---------------------------------------------------------------------------
__global__ __launch_bounds__(256)
void att_e_kernel(const float* __restrict__ p_att,
                  const float* __restrict__ att_h,
                  const float* __restrict__ alpha_w,
                  const float* __restrict__ alpha_b,
                  float* __restrict__ e)
{
    const int wave = threadIdx.x >> 6;
    const int lane = threadIdx.x & 63;
    const int row  = blockIdx.x * 4 + wave;
    if (row >= kB * kL) return;
    const int b = row / kL;
    const float* pr = p_att + (size_t)row * kH + lane * 8;
    const float* ah = att_h + b * kH + lane * 8;
    const float* aw = alpha_w + lane * 8;
    float4 p0 = *(const float4*)pr;
    float4 p1 = *(const float4*)(pr + 4);
    float acc = 0.f;
    const float* pv = (const float*)&p0;
    #pragma unroll
    for (int j = 0; j < 4; ++j) acc += tanhf(pv[j] + ah[j]) * aw[j];
    const float* pw = (const float*)&p1;
    #pragma unroll
    for (int j = 0; j < 4; ++j) acc += tanhf(pw[j] + ah[4 + j]) * aw[4 + j];
    #pragma unroll
    for (int off = 32; off; off >>= 1) acc += __shfl_down(acc, off, 64);
    if (lane == 0) e[row] = acc + alpha_b[0];
}

// ---------------------------------------------------------------------------
// per-block (fc, b): softmax over L + att_res[b,f] = sum_l w[l]*att_feats[b,l,f]
// ---------------------------------------------------------------------------
__global__ __launch_bounds__(256)
void att_softmax_res_kernel(const float* __restrict__ e,
                            const float* __restrict__ att_feats,
                            float* __restrict__ att_res)
{
    __shared__ float wsm[kL];
    __shared__ float red[256];
    const int b   = blockIdx.y;
    const int tid = threadIdx.x;

    const float v = (tid < kL) ? e[b * kL + tid] : -1e30f;
    red[tid] = v; __syncthreads();
    for (int s = 128; s > 0; s >>= 1) {
        if (tid < s) red[tid] = fmaxf(red[tid], red[tid + s]);
        __syncthreads();
    }
    const float mx = red[0];
    __syncthreads();
    const float ex = (tid < kL) ? expf(v - mx) : 0.f;
    red[tid] = ex; __syncthreads();
    for (int s = 128; s > 0; s >>= 1) {
        if (tid < s) red[tid] += red[tid + s];
        __syncthreads();
    }
    const float isum = 1.f / red[0];
    if (tid < kL) wsm[tid] = ex * isum;
    __syncthreads();

    const int f = blockIdx.x * 256 + tid;
    const float* af = att_feats + (size_t)b * kL * kF + f;
    float acc = 0.f;
    #pragma unroll 4
    for (int l = 0; l < kL; ++l) acc += wsm[l] * af[(size_t)l * kF];
    att_res[b * kF + f] = acc;
}

// ---------------------------------------------------------------------------
// Fused LSTM step: sums = h_in@h2h_w.T + att_res@a2c_w.T + i2h_pre[b,t] + biases
//                  -> gates -> c, h_out, h_all[b*T+t]
// grid 512 blocks: block handles r-columns {2*blk, 2*blk+1} for all 64 b.
// ---------------------------------------------------------------------------
__global__ __launch_bounds__(256)
void lstm_fused_kernel(const float* __restrict__ h_in,
                       const float* __restrict__ att_res,
                       const float* __restrict__ i2h_pre,
                       const float* __restrict__ h2h_w,
                       const float* __restrict__ h2h_b,
                       const float* __restrict__ a2c_w,
                       const float* __restrict__ a2c_b,
                       float* __restrict__ h_out,
                       float* __restrict__ cbuf,
                       float* __restrict__ h_all,
                       int t)
{
    __shared__ float hs[64][68];
    __shared__ float ws[10][68];
    const int blk = blockIdx.x;
    const int tid = threadIdx.x;
    const int bq = tid >> 4, s = tid & 15;
    const int rc0 = blk * 2;
    const int kk = s * 4;
    float acc[4][10];
    #pragma unroll
    for (int i = 0; i < 4; ++i)
        #pragma unroll
        for (int rw = 0; rw < 10; ++rw) acc[i][rw] = 0.f;

    // h2h: K = 1024, 10 rows = 5 gates x 2 r
    for (int k0 = 0; k0 < kR; k0 += 64) {
        for (int i = tid; i < 1024; i += 256) {
            const int bl = i >> 4, c4 = (i & 15) * 4;
            *(float4*)&hs[bl][c4] = *(const float4*)&h_in[bl * kR + k0 + c4];
        }
        for (int i = tid; i < 160; i += 256) {
            const int rw = i >> 4, c4 = (i & 15) * 4;
            *(float4*)&ws[rw][c4] =
                *(const float4*)&h2h_w[(size_t)((rw >> 1) * kR + rc0 + (rw & 1)) * kR + k0 + c4];
        }
        __syncthreads();
        float4 hv[4];
        #pragma unroll
        for (int i = 0; i < 4; ++i) hv[i] = *(const float4*)&hs[bq * 4 + i][kk];
        #pragma unroll
        for (int rw = 0; rw < 10; ++rw) {
            const float4 wv = *(const float4*)&ws[rw][kk];
            #pragma unroll
            for (int i = 0; i < 4; ++i)
                acc[i][rw] += hv[i].x * wv.x + hv[i].y * wv.y + hv[i].z * wv.z + hv[i].w * wv.w;
        }
        __syncthreads();
    }
    // a2c: K = 2048, 4 rows -> acc rows 6..9
    for (int k0 = 0; k0 < kF; k0 += 64) {
        for (int i = tid; i < 1024; i += 256) {
            const int bl = i >> 4, c4 = (i & 15) * 4;
            *(float4*)&hs[bl][c4] = *(const float4*)&att_res[bl * kF + k0 + c4];
        }
        for (int i = tid; i < 64; i += 256) {
            const int rw = i >> 4, c4 = (i & 15) * 4;
            *(float4*)&ws[rw][c4] =
                *(const float4*)&a2c_w[(size_t)((rw >> 1) * kR + rc0 + (rw & 1)) * kF + k0 + c4];
        }
        __syncthreads();
        float4 av[4];
        #pragma unroll
        for (int i = 0; i < 4; ++i) av[i] = *(const float4*)&hs[bq * 4 + i][kk];
        #pragma unroll
        for (int rw = 0; rw < 4; ++rw) {
            const float4 wv = *(const float4*)&ws[rw][kk];
            #pragma unroll
            for (int i = 0; i < 4; ++i)
                acc[i][6 + rw] += av[i].x * wv.x + av[i].y * wv.y + av[i].z * wv.z + av[i].w * wv.w;
        }
        __syncthreads();
    }
    // reduce over 16-way k-split (s = low 4 bits of lane)
    #pragma unroll
    for (int i = 0; i < 4; ++i)
        #pragma unroll
        for (int rw = 0; rw < 10; ++rw) {
            float v = acc[i][rw];
            v += __shfl_xor(v, 1, 64); v += __shfl_xor(v, 2, 64);
            v += __shfl_xor(v, 4, 64); v += __shfl_xor(v, 8, 64);
            acc[i][rw] = v;
        }
    if (s == 0) {
        #pragma unroll
        for (int i = 0; i < 4; ++i) {
            const int b = bq * 4 + i;
            const float* ib = i2h_pre + (size_t)(b * kT + t) * (5 * kR);
            #pragma unroll
            for (int rr = 0; rr < 2; ++rr) {
                const int r = rc0 + rr;
                const float S0 = acc[i][0 + rr] + ib[r]          + h2h_b[r];
                const float S1 = acc[i][2 + rr] + ib[kR + r]     + h2h_b[kR + r];
                const float S2 = acc[i][4 + rr] + ib[2 * kR + r] + h2h_b[2 * kR + r];
                const float S3 = acc[i][6 + rr] + ib[3 * kR + r] + h2h_b[3 * kR + r] + a2c_b[r];
                const float S4 = acc[i][8 + rr] + ib[4 * kR + r] + h2h_b[4 * kR + r] + a2c_b[kR + r];
                const float ing = 1.f / (1.f + expf(-S0));
                const float fg  = 1.f / (1.f + expf(-S1));
                const float og  = 1.f / (1.f + expf(-S2));
                const float gg  = fmaxf(S3, S4);
                const float nc  = fg * cbuf[b * kR + r] + ing * gg;
                const float nh  = og * tanhf(nc);
                cbuf[b * kR + r] = nc;
                h_out[b * kR + r] = nh;
                h_all[(size_t)(b * kT + t) * kR + r] = nh;
            }
        }
    }
}

// ---------------------------------------------------------------------------
// in-place log_softmax over V; one block per row (grid = kB*kT)
// ---------------------------------------------------------------------------
__global__ __launch_bounds__(256)
void log_softmax_kernel(float* __restrict__ out)
{
    __shared__ float red[256];
    const int tid = threadIdx.x;
    float* row = out + (size_t)blockIdx.x * kV;

    float mx = -1e30f;
    for (int v = tid; v < kV; v += 256) mx = fmaxf(mx, row[v]);
    red[tid] = mx; __syncthreads();
    for (int s = 128; s > 0; s >>= 1) {
        if (tid < s) red[tid] = fmaxf(red[tid], red[tid + s]);
        __syncthreads();
    }
    mx = red[0];
    __syncthreads();

    float sum = 0.f;
    for (int v = tid; v < kV; v += 256) sum += expf(row[v] - mx);
    red[tid] = sum; __syncthreads();
    for (int s = 128; s > 0; s >>= 1) {
        if (tid < s) red[tid] += red[tid + s];
        __syncthreads();
    }
    const float ls = mx + logf(red[0]);

    for (int v = tid; v < kV; v += 256) row[v] -= ls;
}

extern "C" void kernel_launch(void* const* d_in, const int* in_sizes, int n_in,
                              void* d_out, int out_size, void* d_ws, size_t ws_size,
                              hipStream_t stream)
{
    const int*   seq       = (const int*)  d_in[0];
    const float* att_feats = (const float*)d_in[1];
    const float* embed_w   = (const float*)d_in[2];
    const float* ctx2att_w = (const float*)d_in[3];
    const float* ctx2att_b = (const float*)d_in[4];
    const float* h2att_w   = (const float*)d_in[5];
    const float* h2att_b   = (const float*)d_in[6];
    const float* alpha_w   = (const float*)d_in[7];
    const float* alpha_b   = (const float*)d_in[8];
    const float* i2h_w     = (const float*)d_in[9];
    const float* i2h_b     = (const float*)d_in[10];
    const float* h2h_w     = (const float*)d_in[11];
    const float* h2h_b     = (const float*)d_in[12];
    const float* a2c_w     = (const float*)d_in[13];
    const float* a2c_b     = (const float*)d_in[14];
    const float* logit_w   = (const float*)d_in[15];
    const float* logit_b   = (const float*)d_in[16];
    float* out = (float*)d_out;

    float* ws = (float*)d_ws;
    size_t off = 0;
    auto alloc = [&](size_t nf) { float* p = ws + off; off += (nf + 3) & ~(size_t)3; return p; };

    float* p_att   = alloc((size_t)kB * kL * kH);       // 12544 x 512
    float* i2h_pre = alloc((size_t)kB * kT * 5 * kR);   // 1280 x 5120
    float* h_all   = alloc((size_t)kB * kT * kR);       // 1280 x 1024
    float* att_h   = alloc((size_t)kB * kH);
    float* e_buf   = alloc((size_t)kB * kL);
    float* att_res = alloc((size_t)kB * kF);
    float* h0      = alloc((size_t)kB * kR);
    float* h1      = alloc((size_t)kB * kR);
    float* cbuf    = alloc((size_t)kB * kR);

    hipMemsetAsync(h0,   0, (size_t)kB * kR * sizeof(float), stream);
    hipMemsetAsync(cbuf, 0, (size_t)kB * kR * sizeof(float), stream);

    // p_att = att_feats @ ctx2att_w.T + b  (12544 x 512, K=2048)
    gemm_split_kernel<false><<<dim3(kH / 128, kB * kL / 128), 256, 0, stream>>>(
        att_feats, kF, ctx2att_w, kF, ctx2att_b, p_att, kH, kB * kL, kH, kF, nullptr);

    // i2h_pre = embed[seq] @ i2h_w.T + b   (1280 x 5120, K=300)
    gemm_split_kernel<true><<<dim3(5 * kR / 128, kB * kT / 128), 256, 0, stream>>>(
        embed_w, kE, i2h_w, kE, i2h_b, i2h_pre, 5 * kR, kB * kT, 5 * kR, kE, seq);

    // 20-step recurrence: 4 launches per step, ordering via stream
    float* hin = h0;
    float* hout = h1;
    for (int t = 0; t < kT; ++t) {
        att_h_kernel<<<dim3(4, kB), 256, 0, stream>>>(hin, h2att_w, h2att_b, att_h);
        att_e_kernel<<<dim3(kB * kL / 4), 256, 0, stream>>>(p_att, att_h, alpha_w, alpha_b, e_buf);
        att_softmax_res_kernel<<<dim3(kF / 256, kB), 256, 0, stream>>>(e_buf, att_feats, att_res);
        lstm_fused_kernel<<<dim3(512), 256, 0, stream>>>(
            hin, att_res, i2h_pre, h2h_w, h2h_b, a2c_w, a2c_b, hout, cbuf, h_all, t);
        float* tmp = hin; hin = hout; hout = tmp;
    }

    // logits = h_all @ logit_w.T + b  (1280 x 12001, K=1024) -> out fp32
    gemm_split_kernel<false><<<dim3((kV + 127) / 128, kB * kT / 128), 256, 0, stream>>>(
        h_all, kR, logit_w, kR, logit_b, out, kV, kB * kT, kV, kR, nullptr);

    log_softmax_kernel<<<dim3(kB * kT), 256, 0, stream>>>(out);
}